// Round 1
// 2056.983 us; speedup vs baseline: 1.0198x; 1.0198x over previous
//
#include <hip/hip_runtime.h>

#define VOCAB   32000
#define BSZ     8
#define SEQLEN  2048
#define BOS_ID  1
#define HWORDS  (VOCAB / 2)   // 16000 u32 words, each = 2 packed u16 counts
#define ROW4    (VOCAB / 4)   // 8000 float4 per (b,s) row

typedef float f32x4 __attribute__((ext_vector_type(4)));

// ---------------------------------------------------------------- predict
// Fused zero + histogram + argmax. One block per batch row.
// 16-bit packed LDS histogram: counts <= SEQLEN = 2048 < 65536, so
// atomicAdd(1 << 16*(t&1)) on the containing u32 can never carry across
// the halfword boundary.
__global__ __launch_bounds__(1024)
void wm_predict(const int* __restrict__ ids, int* __restrict__ pred) {
    __shared__ unsigned cnt[HWORDS];              // 64000 B
    const int b   = blockIdx.x;
    const int tid = threadIdx.x;

    for (int i = tid; i < HWORDS; i += 1024) cnt[i] = 0;
    __syncthreads();

    const int* row = ids + b * SEQLEN;
    for (int s = tid; s < SEQLEN; s += 1024) {
        int t = row[s];
        if (t > BOS_ID)   // excludes pad(0) and BOS(1); tokens < VOCAB
            atomicAdd(&cnt[t >> 1], 1u << ((t & 1) << 4));
    }
    __syncthreads();

    // Per-thread scan, ascending indices + strictly-greater => lowest index
    // wins ties within a thread.
    int best_c = 0;
    int best_i = VOCAB;   // sentinel above any real index
    for (int w = tid; w < HWORDS; w += 1024) {
        unsigned x = cnt[w];
        int c0 = (int)(x & 0xffffu);
        int c1 = (int)(x >> 16);
        if (c0 > best_c) { best_c = c0; best_i = 2 * w; }
        if (c1 > best_c) { best_c = c1; best_i = 2 * w + 1; }
    }
    __syncthreads();      // done reading cnt; reuse it as reduction scratch

    int* sc = (int*)cnt;          // [0,1024)
    int* si = sc + 1024;          // [1024,2048) -- 8 KB << 64000 B
    sc[tid] = best_c;
    si[tid] = best_i;
    __syncthreads();
    for (int off = 512; off > 0; off >>= 1) {
        if (tid < off) {
            int c2 = sc[tid + off];
            int i2 = si[tid + off];
            if (c2 > sc[tid] || (c2 == sc[tid] && i2 < si[tid])) {
                sc[tid] = c2;
                si[tid] = i2;
            }
        }
        __syncthreads();
    }
    if (tid == 0) pred[b] = (sc[0] == 0) ? BOS_ID : si[0];
}

// ---------------------------------------------------------------- fill+spike
// One block per (b,s) row (16384 blocks). Writes the whole row including the
// +6 spike at pred[b] -- no separate scatter pass, no div/mod in the loop.
// Nontemporal dwordx4 stores: pure streaming write, zero reuse.
__global__ __launch_bounds__(256)
void wm_fill_spike(f32x4* __restrict__ out, const int* __restrict__ pred) {
    const int r  = blockIdx.x;          // flat (b,s) row index
    const int p  = pred[r >> 11];       // SEQLEN = 2048 = 1<<11 (uniform load)
    const int p4 = p >> 2;
    f32x4* row = out + (long long)r * ROW4;

    const f32x4 neg = { -6.0f, -6.0f, -6.0f, -6.0f };
    f32x4 spike;
    spike[0] = ((p & 3) == 0) ? 6.0f : -6.0f;
    spike[1] = ((p & 3) == 1) ? 6.0f : -6.0f;
    spike[2] = ((p & 3) == 2) ? 6.0f : -6.0f;
    spike[3] = ((p & 3) == 3) ? 6.0f : -6.0f;

    #pragma unroll 4
    for (int j = threadIdx.x; j < ROW4; j += 256) {
        f32x4 v = (j == p4) ? spike : neg;
        __builtin_nontemporal_store(v, row + j);
    }
}

extern "C" void kernel_launch(void* const* d_in, const int* in_sizes, int n_in,
                              void* d_out, int out_size, void* d_ws, size_t ws_size,
                              hipStream_t stream) {
    const int* ids = (const int*)d_in[0];
    f32x4* out = (f32x4*)d_out;
    int* pred = (int*)d_ws;   // 32 B of workspace; poisoned 0xAA, fully rewritten

    // 1) fused zero+histogram+argmax, one block per row
    wm_predict<<<BSZ, 1024, 0, stream>>>(ids, pred);
    // 2) fused -6 fill + +6 spike, one block per (b,s) row
    wm_fill_spike<<<BSZ * SEQLEN, 256, 0, stream>>>(out, pred);
}

// Round 2
// 1991.476 us; speedup vs baseline: 1.0534x; 1.0329x over previous
//
#include <hip/hip_runtime.h>

#define VOCAB   32000
#define BSZ     8
#define SEQLEN  2048
#define BOS_ID  1
#define HWORDS  (VOCAB / 2)   // 16000 u32 words, each = 2 packed u16 counts

// ---------------------------------------------------------------- predict
// Fused zero + histogram + argmax. One block per batch row.
// 16-bit packed LDS histogram: counts <= SEQLEN = 2048 < 65536, so
// atomicAdd(1 << 16*(t&1)) on the containing u32 can never carry across
// the halfword boundary.
__global__ __launch_bounds__(1024)
void wm_predict(const int* __restrict__ ids, int* __restrict__ pred) {
    __shared__ unsigned cnt[HWORDS];              // 64000 B
    const int b   = blockIdx.x;
    const int tid = threadIdx.x;

    for (int i = tid; i < HWORDS; i += 1024) cnt[i] = 0;
    __syncthreads();

    const int* row = ids + b * SEQLEN;
    for (int s = tid; s < SEQLEN; s += 1024) {
        int t = row[s];
        if (t > BOS_ID)   // excludes pad(0) and BOS(1); tokens < VOCAB
            atomicAdd(&cnt[t >> 1], 1u << ((t & 1) << 4));
    }
    __syncthreads();

    // Per-thread scan: ascending indices + strictly-greater => lowest index
    // wins ties within a thread.
    int best_c = 0;
    int best_i = VOCAB;   // sentinel above any real index
    for (int w = tid; w < HWORDS; w += 1024) {
        unsigned x = cnt[w];
        int c0 = (int)(x & 0xffffu);
        int c1 = (int)(x >> 16);
        if (c0 > best_c) { best_c = c0; best_i = 2 * w; }
        if (c1 > best_c) { best_c = c1; best_i = 2 * w + 1; }
    }
    __syncthreads();      // done reading cnt; reuse it as reduction scratch

    int* sc = (int*)cnt;          // [0,1024)
    int* si = sc + 1024;          // [1024,2048) -- 8 KB << 64000 B
    sc[tid] = best_c;
    si[tid] = best_i;
    __syncthreads();
    for (int off = 512; off > 0; off >>= 1) {
        if (tid < off) {
            int c2 = sc[tid + off];
            int i2 = si[tid + off];
            if (c2 > sc[tid] || (c2 == sc[tid] && i2 < si[tid])) {
                sc[tid] = c2;
                si[tid] = i2;
            }
        }
        __syncthreads();
    }
    if (tid == 0) pred[b] = (sc[0] == 0) ? BOS_ID : si[0];
}

// ---------------------------------------------------------------- spike
// 16384 scattered stores of +6 at out[b, s, pred[b]], after the bulk memset.
__global__ void wm_spike(float* __restrict__ out, const int* __restrict__ pred) {
    int i = blockIdx.x * blockDim.x + threadIdx.x;  // [0, BSZ*SEQLEN)
    if (i < BSZ * SEQLEN) {
        int b = i >> 11;                            // SEQLEN = 2048
        out[(long long)i * VOCAB + pred[b]] = 6.0f;
    }
}

extern "C" void kernel_launch(void* const* d_in, const int* in_sizes, int n_in,
                              void* d_out, int out_size, void* d_ws, size_t ws_size,
                              hipStream_t stream) {
    const int* ids = (const int*)d_in[0];
    float* out = (float*)d_out;
    int* pred = (int*)d_ws;   // 32 B of workspace; poisoned 0xAA, fully rewritten

    // 1) bulk fill of -6.0f (bit pattern 0xC0C00000) via the rocclr
    //    fillBufferAligned path -- the same kernel the harness poison uses,
    //    which profiles at ~6.15 TB/s of pure writes (2x our hand-rolled
    //    streaming-store kernels). Async + stream => graph-capturable.
    hipMemsetD32Async((hipDeviceptr_t)out, 0xC0C00000,
                      (size_t)BSZ * SEQLEN * VOCAB, stream);
    // 2) fused zero+histogram+argmax, one block per row
    wm_predict<<<BSZ, 1024, 0, stream>>>(ids, pred);
    // 3) rewrite the +6 spikes (16384 scattered dword stores)
    wm_spike<<<(BSZ * SEQLEN + 255) / 256, 256, 0, stream>>>(out, pred);
}